// Round 19
// baseline (154.722 us; speedup 1.0000x reference)
//
#include <hip/hip_runtime.h>

typedef __bf16 bf16;
typedef __bf16 bf16x8 __attribute__((ext_vector_type(8)));
typedef float f32x4 __attribute__((ext_vector_type(4)));

#define MFMA16(a, b, c) __builtin_amdgcn_mfma_f32_16x16x32_bf16((a), (b), (c), 0, 0, 0)

constexpr int B_ = 2, S_ = 2048, D_ = 1024, H_ = 16, DK_ = 64;

__device__ __forceinline__ void gload16(const bf16* g, bf16* l)
{
  __builtin_amdgcn_global_load_lds(
      (const __attribute__((address_space(1))) uint32_t*)g,
      (__attribute__((address_space(3))) uint32_t*)l, 16, 0, 0);
}

// reg-stage 8 f32 -> bf16x8 -> swizzled LDS slot (logical row, c8)
__device__ __forceinline__ void stage_f32(const float* src, bf16* lds, int row, int c8)
{
  float4 a4 = ((const float4*)src)[0];
  float4 b4 = ((const float4*)src)[1];
  bf16x8 v = {(bf16)a4.x, (bf16)a4.y, (bf16)a4.z, (bf16)a4.w,
              (bf16)b4.x, (bf16)b4.y, (bf16)b4.z, (bf16)b4.w};
  *(bf16x8*)&lds[row * 64 + ((c8 ^ (row & 7)) << 3)] = v;
}

// ---------------------------------------------------------------------------
// 128x128-tile GEMM, BK=64, 4 waves (2x2), 64x64 acc per wave (m97 structure).
// A: f32 (reg-staged with inline cvt) or bf16 (swizzled gload_lds).
// W: f32, reg-staged with inline cvt. No separate conversion pass needed.
// PERM==0: Y[m*1024+n]. PERM==1: scatter to (B,H,S,DK), *scale0 for z==0.
// ---------------------------------------------------------------------------
template <typename TX, typename TY, int PERM>
__global__ __launch_bounds__(256) void gemm_k(
    const TX* __restrict__ A,
    const float* __restrict__ W0, const float* __restrict__ W1, const float* __restrict__ W2,
    TY* __restrict__ Y0, TY* __restrict__ Y1, TY* __restrict__ Y2,
    int Kdim, float scale0)
{
  __shared__ __align__(16) bf16 As[128 * 64];
  __shared__ __align__(16) bf16 Bs[128 * 64];
  const int t = threadIdx.x, l = t & 63, w = t >> 6;
  const int wm = w >> 1, wn = w & 1;
  const int m0 = blockIdx.x * 128, n0 = blockIdx.y * 128;
  const int z = blockIdx.z;
  const float* W = z == 0 ? W0 : z == 1 ? W1 : W2;
  TY* Y = z == 0 ? Y0 : z == 1 ? Y1 : Y2;
  const float scale = (PERM == 1 && z == 0) ? scale0 : 1.0f;

  f32x4 acc[4][4] = {};

  for (int k0 = 0; k0 < Kdim; k0 += 64) {
    __syncthreads();
#pragma unroll
    for (int j = 0; j < 4; ++j) {
      int slot = j * 256 + t;
      int row = slot >> 3, c8 = slot & 7;
      if constexpr (sizeof(TX) == 4) {
        stage_f32((const float*)A + (size_t)(m0 + row) * Kdim + k0 + c8 * 8, As, row, c8);
      } else {
        gload16((const bf16*)A + (size_t)(m0 + row) * Kdim + k0 + ((c8 ^ (row & 7)) << 3),
                &As[(j * 256 + w * 64) * 8]);
      }
      stage_f32(W + (size_t)(n0 + row) * Kdim + k0 + c8 * 8, Bs, row, c8);
    }
    if constexpr (sizeof(TX) == 2)
      asm volatile("s_waitcnt vmcnt(0)" ::: "memory");
    __syncthreads();
#pragma unroll
    for (int kk = 0; kk < 2; ++kk) {
      bf16x8 af[4], bfr[4];
#pragma unroll
      for (int i = 0; i < 4; ++i) {
        int Ra = wm * 64 + i * 16 + (l & 15);
        int Rb = wn * 64 + i * 16 + (l & 15);
        int c = kk * 4 + (l >> 4);
        af[i] = *(const bf16x8*)&As[Ra * 64 + ((c ^ (Ra & 7)) << 3)];
        bfr[i] = *(const bf16x8*)&Bs[Rb * 64 + ((c ^ (Rb & 7)) << 3)];
      }
#pragma unroll
      for (int mi = 0; mi < 4; ++mi)
#pragma unroll
        for (int ni = 0; ni < 4; ++ni)
          acc[mi][ni] = MFMA16(af[mi], bfr[ni], acc[mi][ni]);
    }
  }

#pragma unroll
  for (int mi = 0; mi < 4; ++mi)
#pragma unroll
    for (int ni = 0; ni < 4; ++ni)
#pragma unroll
      for (int j = 0; j < 4; ++j) {
        int m = m0 + wm * 64 + mi * 16 + (l >> 4) * 4 + j;
        int n = n0 + wn * 64 + ni * 16 + (l & 15);
        float v = acc[mi][ni][j] * scale;
        if (PERM == 0) {
          Y[(size_t)m * 1024 + n] = (TY)v;
        } else {
          int b = m >> 11, s = m & (S_ - 1), h = n >> 6, d = n & (DK_ - 1);
          Y[(((size_t)(b * H_ + h)) * S_ + s) * DK_ + d] = (TY)v;
        }
      }
}

// ---------------------------------------------------------------------------
// RoPE in-place on K only (Q rope is fused into the attention prologue).
// ---------------------------------------------------------------------------
__global__ __launch_bounds__(256) void rope_k(
    bf16* __restrict__ K, const int* __restrict__ pos)
{
  int idx = blockIdx.x * 256 + threadIdx.x;        // 262144 threads
  int kpg = idx & 3;
  int s = (idx >> 2) & (S_ - 1);
  int bh = idx >> 13;
  float p = (float)pos[s];
  size_t off = ((size_t)bh * S_ + s) * DK_ + kpg * 16;
  bf16x8 lo = *(const bf16x8*)(K + off);
  bf16x8 hi = *(const bf16x8*)(K + off + 8);
  bf16x8 olo, ohi;
#pragma unroll
  for (int ii = 0; ii < 8; ++ii) {
    int kp = kpg * 8 + ii;
    float ang = p * exp2f((float)kp * -0.41524101186017f);  // log2(10000)/32
    float sn, cs;
    __sincosf(ang, &sn, &cs);
    float x0 = (float)((ii < 4 ? lo : hi)[(ii & 3) * 2]);
    float x1 = (float)((ii < 4 ? lo : hi)[(ii & 3) * 2 + 1]);
    bf16 o0 = (bf16)(x0 * cs - x1 * sn);
    bf16 o1 = (bf16)(x0 * sn + x1 * cs);
    if (ii < 4) { olo[(ii & 3) * 2] = o0; olo[(ii & 3) * 2 + 1] = o1; }
    else        { ohi[(ii & 3) * 2] = o0; ohi[(ii & 3) * 2 + 1] = o1; }
  }
  *(bf16x8*)(K + off) = olo;
  *(bf16x8*)(K + off + 8) = ohi;
}

// ---------------------------------------------------------------------------
// De-paired causal flash attention (R14-verified), no-max softmax, Q-rope
// fused in prologue. V: register-transpose into XOR-swizzled [d][kv] LDS.
// Grid 1024 = (bh, i), balanced qt map; 4 blocks/CU (LDS = 40960 B).
// ---------------------------------------------------------------------------
__global__ __launch_bounds__(256, 4) void attn_k(
    const bf16* __restrict__ Q, const bf16* __restrict__ K, const bf16* __restrict__ V,
    const int* __restrict__ pos, bf16* __restrict__ O)
{
  __shared__ __align__(16) bf16 Klds[2][64 * 64];   // 16384 B
  __shared__ __align__(16) bf16 Vt[2][64 * 64];     // 16384 B, swizzled [d][kv]
  __shared__ __align__(16) bf16 Ps[4][16 * 64];     // 8192 B, swizzled per wave

  const int t = threadIdx.x, l = t & 63, w = t >> 6;
  const int bx = blockIdx.x;
  const int i5 = bx >> 5;                    // 0..31
  const int bh = bx & 31;
  const int a = i5 & 7, bq = i5 >> 3;
  const int qt = (bq == 0) ? (31 - a) : (bq == 1) ? a : (bq == 2) ? (16 + a) : (15 - a);
  const int b = bh >> 4, h = bh & 15;
  const size_t base = (size_t)bh * S_ * DK_;
  const int q0 = qt * 64;

  // Q fragments + fused RoPE (Q pre-scaled by log2e/8 in projection epilogue)
  const int qrow = w * 16 + (l & 15), qcol = (l >> 4) * 8;
  const bf16* pq = Q + base + (size_t)(q0 + qrow) * 64 + qcol;
  bf16x8 aq0 = *(const bf16x8*)pq, aq1 = *(const bf16x8*)(pq + 32);
  {
    float p = (float)pos[q0 + qrow];
#pragma unroll
    for (int i2 = 0; i2 < 4; ++i2) {
      int kp = (l >> 4) * 4 + i2;
      float s0, c0, s1, c1;
      __sincosf(p * exp2f((float)kp * -0.41524101186017f), &s0, &c0);
      __sincosf(p * exp2f((float)(kp + 16) * -0.41524101186017f), &s1, &c1);
      float x0 = (float)aq0[2 * i2], x1 = (float)aq0[2 * i2 + 1];
      aq0[2 * i2] = (bf16)(x0 * c0 - x1 * s0);
      aq0[2 * i2 + 1] = (bf16)(x0 * s0 + x1 * c0);
      x0 = (float)aq1[2 * i2]; x1 = (float)aq1[2 * i2 + 1];
      aq1[2 * i2] = (bf16)(x0 * c1 - x1 * s1);
      aq1[2 * i2 + 1] = (bf16)(x0 * s1 + x1 * c1);
    }
  }

  // prologue: stage K[0] (swizzled gload_lds) + V[0] (regs -> swizzled LDS)
  {
#pragma unroll
    for (int j = 0; j < 2; ++j) {
      int slot = j * 256 + t, row = slot >> 3, c8 = slot & 7;
      gload16(K + base + (size_t)row * 64 + ((c8 ^ (row & 7)) << 3),
              &Klds[0][(j * 256 + w * 64) * 8]);
    }
    const bf16* pv = V + base + (size_t)l * 64 + w * 16;
    bf16x8 v0 = *(const bf16x8*)pv, v1 = *(const bf16x8*)(pv + 8);
    asm volatile("s_waitcnt vmcnt(0)" ::: "memory");
#pragma unroll
    for (int ii = 0; ii < 8; ++ii) {
      int d0 = w * 16 + ii, d1 = w * 16 + 8 + ii;
      Vt[0][d0 * 64 + (((l >> 3) ^ (d0 & 7)) << 3) + (l & 7)] = v0[ii];
      Vt[0][d1 * 64 + (((l >> 3) ^ (d1 & 7)) << 3) + (l & 7)] = v1[ii];
    }
  }
  __syncthreads();

  f32x4 acc[4] = {};
  float lsum[4] = {0.f, 0.f, 0.f, 0.f};   // in-lane partial row-sums

  int cur = 0;
  for (int tk = 0; tk <= qt; ++tk) {
    const int nxt = cur ^ 1;
    const bool hasn = tk < qt;
    bf16x8 v0, v1;
    if (hasn) {  // issue next tile's loads before compute (async-stage split)
      const int kv0n = (tk + 1) * 64;
#pragma unroll
      for (int j = 0; j < 2; ++j) {
        int slot = j * 256 + t, row = slot >> 3, c8 = slot & 7;
        gload16(K + base + (size_t)(kv0n + row) * 64 + ((c8 ^ (row & 7)) << 3),
                &Klds[nxt][(j * 256 + w * 64) * 8]);
      }
      const bf16* pv = V + base + (size_t)(kv0n + l) * 64 + w * 16;
      v0 = *(const bf16x8*)pv;
      v1 = *(const bf16x8*)(pv + 8);
    }

    // S = Q K^T (16 q-rows x 64 kv per wave), swizzled K reads
    f32x4 sc[4];
    __builtin_amdgcn_s_setprio(1);
#pragma unroll
    for (int nf = 0; nf < 4; ++nf) {
      int R = nf * 16 + (l & 15);
      int c0 = l >> 4;
      bf16x8 b0 = *(const bf16x8*)&Klds[cur][R * 64 + ((c0 ^ (R & 7)) << 3)];
      bf16x8 b1 = *(const bf16x8*)&Klds[cur][R * 64 + (((4 + c0) ^ (R & 7)) << 3)];
      f32x4 s = {};
      s = MFMA16(aq0, b0, s);
      s = MFMA16(aq1, b1, s);
      sc[nf] = s;
    }
    __builtin_amdgcn_s_setprio(0);

    if (tk == qt) {  // causal mask on diagonal tile
#pragma unroll
      for (int nf = 0; nf < 4; ++nf)
#pragma unroll
        for (int j = 0; j < 4; ++j) {
          int kvl = nf * 16 + (l & 15);
          int ql = w * 16 + (l >> 4) * 4 + j;
          if (kvl > ql) sc[nf][j] = -1e30f;
        }
    }

    // no-max softmax numerator: p = exp2(sc); masked -> exp2(-1e30) = 0.
#pragma unroll
    for (int nf = 0; nf < 4; ++nf)
#pragma unroll
      for (int j = 0; j < 4; ++j) {
        float p = exp2f(sc[nf][j]);
        lsum[j] += p;
        int r = (l >> 4) * 4 + j, c = nf * 16 + (l & 15);
        Ps[w][r * 64 + ((((c >> 3) ^ (r & 7))) << 3) + (c & 7)] = (bf16)p;
      }

    // our Ps writes visible to our reads
    asm volatile("s_waitcnt lgkmcnt(0)" ::: "memory");

    // O += P V (swizzled Ps + Vt reads)
    __builtin_amdgcn_s_setprio(1);
#pragma unroll
    for (int kk = 0; kk < 2; ++kk) {
      int rp = l & 15;
      int c8p = kk * 4 + (l >> 4);
      bf16x8 ap = *(const bf16x8*)&Ps[w][rp * 64 + ((c8p ^ (rp & 7)) << 3)];
#pragma unroll
      for (int nf = 0; nf < 4; ++nf) {
        int R = nf * 16 + (l & 15);
        bf16x8 bv = *(const bf16x8*)&Vt[cur][R * 64 + ((c8p ^ (R & 7)) << 3)];
        acc[nf] = MFMA16(ap, bv, acc[nf]);
      }
    }
    __builtin_amdgcn_s_setprio(0);

    if (hasn) {  // land next V into the other buffer (conflict-free swizzled writes)
#pragma unroll
      for (int ii = 0; ii < 8; ++ii) {
        int d0 = w * 16 + ii, d1 = w * 16 + 8 + ii;
        Vt[nxt][d0 * 64 + (((l >> 3) ^ (d0 & 7)) << 3) + (l & 7)] = v0[ii];
        Vt[nxt][d1 * 64 + (((l >> 3) ^ (d1 & 7)) << 3) + (l & 7)] = v1[ii];
      }
      asm volatile("s_waitcnt vmcnt(0)" ::: "memory");  // K[nxt] landed
    }
    __syncthreads();
    cur = nxt;
  }

  // epilogue: single cross-lane lsum reduction, normalize, write O
#pragma unroll
  for (int m = 1; m <= 8; m <<= 1)
#pragma unroll
    for (int j = 0; j < 4; ++j)
      lsum[j] += __shfl_xor(lsum[j], m, 64);

#pragma unroll
  for (int nf = 0; nf < 4; ++nf)
#pragma unroll
    for (int j = 0; j < 4; ++j) {
      int r = w * 16 + (l >> 4) * 4 + j;
      int d = nf * 16 + (l & 15);
      O[((size_t)(b * S_ + q0 + r) * H_ + h) * DK_ + d] = (bf16)(acc[nf][j] / lsum[j]);
    }
}

// ---------------------------------------------------------------------------
extern "C" void kernel_launch(void* const* d_in, const int* in_sizes, int n_in,
                              void* d_out, int out_size, void* d_ws, size_t ws_size,
                              hipStream_t stream)
{
  const float* x = (const float*)d_in[0];
  const float* Wq = (const float*)d_in[1];
  const float* Wk = (const float*)d_in[2];
  const float* Wv = (const float*)d_in[3];
  const float* Wo = (const float*)d_in[4];
  const int* pos = (const int*)d_in[5];

  bf16* ws = (bf16*)d_ws;
  const size_t NE = (size_t)B_ * H_ * S_ * DK_;  // 4,194,304
  bf16* Qb = ws;
  bf16* Kb = Qb + NE;
  bf16* Vb = Kb + NE;
  bf16* Ob = Vb + NE;

  dim3 blk(256);

  // fused QKV projection: A = f32 x (inline cvt), W = f32 (inline cvt).
  // Q prescale folds 1/sqrt(DK) * log2(e) so attention can use exp2 directly.
  hipLaunchKernelGGL((gemm_k<float, bf16, 1>), dim3(32, 8, 3), blk, 0, stream,
                     x, Wq, Wk, Wv, Qb, Kb, Vb, 1024, 0.125f * 1.4426950408889634f);

  // RoPE on K only (Q rope fused into attention prologue)
  hipLaunchKernelGGL(rope_k, dim3(1024), blk, 0, stream, Kb, pos);

  // de-paired balanced flash attention (grid 1024, 4 blocks/CU)
  hipLaunchKernelGGL(attn_k, dim3(1024), blk, 0, stream, Qb, Kb, Vb, pos, Ob);

  // output projection: A = bf16 Ob (gload_lds), W = f32 Wo (inline cvt)
  hipLaunchKernelGGL((gemm_k<bf16, float, 0>), dim3(32, 8, 1), blk, 0, stream,
                     Ob, Wo, Wo, Wo, (float*)d_out, (float*)d_out, (float*)d_out,
                     1024, 1.0f);
}